// Round 2
// baseline (418.679 us; speedup 1.0000x reference)
//
#include <hip/hip_runtime.h>
#include <hip/hip_bf16.h>
#include <stdint.h>

#define QL 1024
#define KL 1024
#define HM 64
#define DD 128
#define SM_SCALE 0.08838834764831845f
#define LDP 136   // 128 + 8 bf16 pad -> 272B row stride, 2-way bank alias (free)

typedef __bf16 bf16x8 __attribute__((ext_vector_type(8)));
typedef __bf16 bf16x4 __attribute__((ext_vector_type(4)));
typedef float floatx4 __attribute__((ext_vector_type(4)));

// =====================================================================
// qk3: one block per (g, qt). Block loops over 16 K-subtiles (64 rows).
//  - Q tile (128x128) converted fp32->bf16 into LDS ONCE per block
//  - K subtile double-buffered: fp32 loads issued at top of iteration
//    (hidden under MFMA+epilogue), cvt+ds_write after, one barrier/iter
//  - swapped-operand MFMA -> lane holds 4 consecutive k -> float4 epilogue
//  - block writes its rows contiguously across kt -> L2 write merge
//  - XCD-chunked: bid&7 = XCD, qt fastest -> K slice (512 KB) reused by
//    8 consecutive blocks on the same XCD
//  - sink column fused; no workspace, single launch
// =====================================================================
__global__ __launch_bounds__(256, 2)
void qk3_kernel(const float* __restrict__ Qg, const float* __restrict__ Kg,
                const float* __restrict__ mask, const float* __restrict__ sinks,
                float* __restrict__ out)
{
    const int bid   = blockIdx.x;      // 0..511
    const int xcd   = bid & 7;
    const int inner = bid >> 3;        // 0..63
    const int qt    = inner & 7;       // fastest -> K-slice L2 reuse
    const int g     = xcd * 8 + (inner >> 3);

    __shared__ __bf16 Qs[128][LDP];    // 34 KB
    __shared__ __bf16 Ks[2][64][LDP];  // 34 KB

    const int t = threadIdx.x;

    // ---- prologue: stage Q (128x128) + K tile 0 (64x128), fp32->bf16 ----
    const float* Qbase = Qg + (size_t)(qt * 128) * (HM * DD) + (size_t)g * DD;
    const float* Kbase = Kg + (size_t)g * DD;
#pragma unroll
    for (int j = 0; j < 16; ++j) {
        int c = t + 256 * j;           // 0..4095
        int row = c >> 5, c4 = c & 31;
        float4 a = *(const float4*)(Qbase + (size_t)row * (HM * DD) + c4 * 4);
        bf16x4 av = { (__bf16)a.x, (__bf16)a.y, (__bf16)a.z, (__bf16)a.w };
        *(bf16x4*)&Qs[row][c4 * 4] = av;
    }
#pragma unroll
    for (int j = 0; j < 8; ++j) {
        int c = t + 256 * j;           // 0..2047
        int row = c >> 5, c4 = c & 31;
        float4 b = *(const float4*)(Kbase + (size_t)row * (HM * DD) + c4 * 4);
        bf16x4 bv = { (__bf16)b.x, (__bf16)b.y, (__bf16)b.z, (__bf16)b.w };
        *(bf16x4*)&Ks[0][row][c4 * 4] = bv;
    }
    __syncthreads();

    const int wave = t >> 6;
    const int lane = t & 63;
    const int wm   = (wave & 1) * 64;  // q offset within tile
    const int wnk  = (wave >> 1) * 32; // k offset within 64-subtile
    const int lr   = lane & 15;
    const int quad = lane >> 4;

    const size_t obase = (size_t)g * QL * 1025;

    for (int kt = 0; kt < 16; ++kt) {
        const int b = kt & 1;

        // ---- issue next K subtile fp32 loads early (hide under compute) ----
        float4 nf[8];
        if (kt < 15) {
            const float* nb = Kg + (size_t)((kt + 1) * 64) * (HM * DD) + (size_t)g * DD;
#pragma unroll
            for (int j = 0; j < 8; ++j) {
                int c = t + 256 * j;
                nf[j] = *(const float4*)(nb + (size_t)(c >> 5) * (HM * DD) + (c & 31) * 4);
            }
        }

        // ---- compute 128x64: 4 waves, each 64q x 32k ----
        floatx4 acc[4][2] = {};
#pragma unroll
        for (int ks = 0; ks < 4; ++ks) {
            const int d0 = ks * 32 + quad * 8;
            bf16x8 af[4], bfr[2];
#pragma unroll
            for (int mi = 0; mi < 4; ++mi)
                af[mi] = *(const bf16x8*)&Qs[wm + mi * 16 + lr][d0];
#pragma unroll
            for (int ni = 0; ni < 2; ++ni)
                bfr[ni] = *(const bf16x8*)&Ks[b][wnk + ni * 16 + lr][d0];
#pragma unroll
            for (int mi = 0; mi < 4; ++mi)
#pragma unroll
                for (int ni = 0; ni < 2; ++ni)
                    acc[mi][ni] = __builtin_amdgcn_mfma_f32_16x16x32_bf16(
                        bfr[ni], af[mi], acc[mi][ni], 0, 0, 0);
        }

        // ---- epilogue: col=lane&15 -> q, row=quad*4+r -> k (swapped) ----
#pragma unroll
        for (int mi = 0; mi < 4; ++mi) {
            const int q = (qt << 7) + wm + mi * 16 + lr;
            const float* mrow = mask + ((size_t)q << 10);
            float* orow = out + obase + (size_t)q * 1025;
#pragma unroll
            for (int ni = 0; ni < 2; ++ni) {
                const int k0 = (kt << 6) + wnk + ni * 16 + (quad << 2);
                floatx4 mv = *(const floatx4*)(mrow + k0);   // 16B aligned
                floatx4 v  = acc[mi][ni] * SM_SCALE + mv;
                __builtin_memcpy((void*)(orow + k0), &v, 16); // 4B-aligned dwordx4
            }
        }

        // ---- convert + write next K subtile into other buffer ----
        if (kt < 15) {
#pragma unroll
            for (int j = 0; j < 8; ++j) {
                int c = t + 256 * j;
                bf16x4 bv = { (__bf16)nf[j].x, (__bf16)nf[j].y,
                              (__bf16)nf[j].z, (__bf16)nf[j].w };
                *(bf16x4*)&Ks[1 - b][c >> 5][(c & 31) * 4] = bv;
            }
            __syncthreads();   // next iter reads Ks[1-b]; also protects Ks[b] reuse
        }
    }

    // ---- fused sink column ----
    if (t < 128) {
        const int q = (qt << 7) + t;
        out[obase + (size_t)q * 1025 + 1024] = sinks[((size_t)g << 10) + q];
    }
}

extern "C" void kernel_launch(void* const* d_in, const int* in_sizes, int n_in,
                              void* d_out, int out_size, void* d_ws, size_t ws_size,
                              hipStream_t stream)
{
    const float* Q     = (const float*)d_in[0];
    const float* K     = (const float*)d_in[1];
    const float* mask  = (const float*)d_in[2];
    const float* sinks = (const float*)d_in[3];
    float* out = (float*)d_out;

    qk3_kernel<<<512, 256, 0, stream>>>(Q, K, mask, sinks, out);
}